// Round 1
// baseline (250.976 us; speedup 1.0000x reference)
//
#include <hip/hip_runtime.h>
#include <hip/hip_bf16.h>

#define NN 8192
#define INC 256
#define OUTC 512
#define NE 262144
#define MAXD 1024

typedef __hip_bfloat16 bf16;

// u[k] = sum_j att_w[j] * W[j][k];  v[k] = sum_j W[j][k]
__global__ __launch_bounds__(256) void k_uv(const float* __restrict__ W,
                                            const float* __restrict__ att_w,
                                            float* __restrict__ u,
                                            float* __restrict__ v) {
  int k = threadIdx.x;
  float su = 0.f, sv = 0.f;
  for (int j = 0; j < OUTC; ++j) {
    float w = W[j * INC + k];
    su = fmaf(att_w[j], w, su);
    sv += w;
  }
  u[k] = su;
  v[k] = sv;
}

// partial column sums of x (deterministic two-stage reduction)
__global__ __launch_bounds__(256) void k_xsum_part(const float* __restrict__ x,
                                                   float* __restrict__ xpart) {
  int t = threadIdx.x, b = blockIdx.x;  // 64 blocks
  float acc = 0.f;
  int r0 = b * (NN / 64);
  for (int r = r0; r < r0 + NN / 64; ++r) acc += x[r * INC + t];
  xpart[b * INC + t] = acc;
}

__global__ __launch_bounds__(256) void k_xsum_red(const float* __restrict__ xpart,
                                                  float* __restrict__ xsum) {
  int t = threadIdx.x;
  float acc = 0.f;
  for (int b = 0; b < 64; ++b) acc += xpart[b * INC + t];
  xsum[t] = acc;
}

// Wc[o][k] = sum_j lin_w[o][j] * W[j][k]   ([512,256])
__global__ __launch_bounds__(256) void k_wc(const float* __restrict__ lin_w,
                                            const float* __restrict__ W,
                                            float* __restrict__ Wc) {
  int o = blockIdx.x, k = threadIdx.x;
  float acc = 0.f;
  for (int j = 0; j < OUTC; ++j) acc = fmaf(lin_w[o * OUTC + j], W[j * INC + k], acc);
  Wc[o * INC + k] = acc;
}

// G_sum[o] = Wc[o][:] . xsum
__global__ __launch_bounds__(256) void k_gsum(const float* __restrict__ Wc,
                                              const float* __restrict__ xsum,
                                              float* __restrict__ gsum) {
  int o = blockIdx.x * 256 + threadIdx.x;
  float acc = 0.f;
  for (int k = 0; k < INC; ++k) acc = fmaf(Wc[o * INC + k], xsum[k], acc);
  gsum[o] = acc;
}

// alpha[i] = leaky_relu( (x[i].u) * (x[i].v), 0.2 )
__global__ __launch_bounds__(256) void k_alpha(const float* __restrict__ x,
                                               const float* __restrict__ u,
                                               const float* __restrict__ v,
                                               float* __restrict__ alpha) {
  __shared__ float s1[256];
  __shared__ float s2[256];
  int i = blockIdx.x, t = threadIdx.x;
  float xv = x[i * INC + t];
  s1[t] = xv * u[t];
  s2[t] = xv * v[t];
  __syncthreads();
  for (int off = 128; off > 0; off >>= 1) {
    if (t < off) { s1[t] += s1[t + off]; s2[t] += s2[t + off]; }
    __syncthreads();
  }
  if (t == 0) {
    float a = s1[0] * s2[0];
    alpha[i] = a > 0.f ? a : 0.2f * a;
  }
}

// g = x @ Wc.T   [8192,256]x[512,256]^T -> [8192,512] bf16
__global__ __launch_bounds__(256) void k_gemm(const float* __restrict__ x,
                                              const float* __restrict__ Wc,
                                              bf16* __restrict__ g) {
  __shared__ float As[64][33];
  __shared__ float Bs[64][33];
  int bx = blockIdx.x;  // 0..7   (OUTC/64)
  int by = blockIdx.y;  // 0..127 (NN/64)
  int tid = threadIdx.x;
  int tx = tid & 15, ty = tid >> 4;
  float acc[4][4] = {{0.f}};
  for (int k0 = 0; k0 < INC; k0 += 32) {
    for (int idx = tid; idx < 64 * 32; idx += 256) {
      int r = idx >> 5, kk = idx & 31;
      As[r][kk] = x[(by * 64 + r) * INC + k0 + kk];
      Bs[r][kk] = Wc[(bx * 64 + r) * INC + k0 + kk];
    }
    __syncthreads();
#pragma unroll
    for (int kk = 0; kk < 32; ++kk) {
      float a[4], b[4];
#pragma unroll
      for (int r = 0; r < 4; ++r) a[r] = As[ty * 4 + r][kk];
#pragma unroll
      for (int c = 0; c < 4; ++c) b[c] = Bs[tx * 4 + c][kk];
#pragma unroll
      for (int r = 0; r < 4; ++r)
#pragma unroll
        for (int c = 0; c < 4; ++c) acc[r][c] = fmaf(a[r], b[c], acc[r][c]);
    }
    __syncthreads();
  }
  for (int r = 0; r < 4; ++r)
    for (int c = 0; c < 4; ++c)
      g[(size_t)(by * 64 + ty * 4 + r) * OUTC + bx * 64 + tx * 4 + c] =
          __float2bfloat16(acc[r][c]);
}

__global__ __launch_bounds__(256) void k_deg(const int* __restrict__ erow, int* __restrict__ deg) {
  int e = blockIdx.x * 256 + threadIdx.x;
  if (e < NE) atomicAdd(&deg[erow[e]], 1);
}

// exclusive scan of deg[8192] -> rowstart[8193], single block of 1024
__global__ __launch_bounds__(1024) void k_scan(const int* __restrict__ deg,
                                               int* __restrict__ rowstart) {
  __shared__ int sums[1024];
  int t = threadIdx.x;
  int base = t * 8;
  int loc[8];
  int s = 0;
#pragma unroll
  for (int j = 0; j < 8; ++j) { loc[j] = s; s += deg[base + j]; }
  sums[t] = s;
  __syncthreads();
  for (int off = 1; off < 1024; off <<= 1) {
    int val = (t >= off) ? sums[t - off] : 0;
    __syncthreads();
    sums[t] += val;
    __syncthreads();
  }
  int prev = (t == 0) ? 0 : sums[t - 1];
#pragma unroll
  for (int j = 0; j < 8; ++j) rowstart[base + j] = prev + loc[j];
  if (t == 1023) rowstart[NN] = sums[1023];
}

__global__ __launch_bounds__(256) void k_scatter(const int* __restrict__ erow,
                                                 const int* __restrict__ ecol,
                                                 const int* __restrict__ rowstart,
                                                 int* __restrict__ cursor,
                                                 int* __restrict__ colbuf) {
  int e = blockIdx.x * 256 + threadIdx.x;
  if (e < NE) {
    int r = erow[e];
    int p = atomicAdd(&cursor[r], 1);
    colbuf[rowstart[r] + p] = ecol[e];
  }
}

// one block per row i: exact softmax row (with multiplicities) applied to g
__global__ __launch_bounds__(256) void k_agg(const float* __restrict__ alpha,
                                             const float* __restrict__ gsum,
                                             const bf16* __restrict__ g,
                                             const int* __restrict__ rowstart,
                                             const int* __restrict__ colbuf,
                                             float* __restrict__ out) {
  __shared__ int cols[MAXD];
  __shared__ float coeff[MAXD];
  __shared__ float redf[256];
  __shared__ int redi[256];
  int i = blockIdx.x, t = threadIdx.x;
  int s = rowstart[i];
  int d = rowstart[i + 1] - s;
  if (d > MAXD) d = MAXD;  // safety; statistically unreachable
  float al = alpha[i];
  for (int k = t; k < d; k += 256) cols[k] = colbuf[s + k];
  __syncthreads();

  // multiplicity + first-occurrence per edge slot (O(d^2), d ~ 32)
  int myM[MAXD / 256];
  unsigned char myF[MAXD / 256];
  int nk = 0;
  int mmax_loc = 0;
  for (int k = t; k < d; k += 256) {
    int c = cols[k];
    int m = 0, first = 1;
    for (int q = 0; q < d; ++q) {
      int cq = cols[q];
      if (cq == c) {
        m++;
        if (q < k) first = 0;
      }
    }
    myM[nk] = m;
    myF[nk] = (unsigned char)first;
    nk++;
    if (m > mmax_loc) mmax_loc = m;
  }
  redi[t] = mmax_loc;
  __syncthreads();
  for (int o = 128; o > 0; o >>= 1) {
    if (t < o) { int b = redi[t + o]; if (b > redi[t]) redi[t] = b; }
    __syncthreads();
  }
  int mmax = redi[0];
  __syncthreads();

  float M = (al > 0.f) ? al * (float)mmax : 0.f;  // row max incl. the zeros
  float eMn = expf(-M);
  float sumExp = 0.f;
  int ncnt = 0;
  nk = 0;
  for (int k = t; k < d; k += 256) {
    float cf = 0.f;
    if (myF[nk]) {
      float w = expf(al * (float)myM[nk] - M);
      sumExp += w;
      ncnt++;
      cf = w - eMn;
    }
    coeff[k] = cf;
    nk++;
  }
  redf[t] = sumExp;
  redi[t] = ncnt;
  __syncthreads();
  for (int o = 128; o > 0; o >>= 1) {
    if (t < o) { redf[t] += redf[t + o]; redi[t] += redi[t + o]; }
    __syncthreads();
  }
  float Z = (float)(NN - redi[0]) * eMn + redf[0];
  float invZ = 1.0f / Z;

  // out[i][2t], out[i][2t+1]
  float acc0 = eMn * gsum[2 * t];
  float acc1 = eMn * gsum[2 * t + 1];
  for (int k = 0; k < d; ++k) {
    float cf = coeff[k];
    if (cf != 0.f) {
      int c = cols[k];
      unsigned int pv = *(const unsigned int*)((const char*)g + ((size_t)c * OUTC + 2 * t) * 2);
      float g0 = __uint_as_float((pv & 0xffffu) << 16);
      float g1 = __uint_as_float((pv >> 16) << 16);
      acc0 = fmaf(cf, g0, acc0);
      acc1 = fmaf(cf, g1, acc1);
    }
  }
  float r0 = acc0 * invZ, r1 = acc1 * invZ;
  out[(size_t)i * OUTC + 2 * t] = r0 > 0.f ? r0 : expm1f(r0);
  out[(size_t)i * OUTC + 2 * t + 1] = r1 > 0.f ? r1 : expm1f(r1);
}

extern "C" void kernel_launch(void* const* d_in, const int* in_sizes, int n_in,
                              void* d_out, int out_size, void* d_ws, size_t ws_size,
                              hipStream_t stream) {
  const float* x = (const float*)d_in[0];
  const int* ei = (const int*)d_in[1];
  const float* W = (const float*)d_in[2];
  const float* att_w = (const float*)d_in[3];
  const float* lin_w = (const float*)d_in[4];
  float* out = (float*)d_out;
  const int* erow = ei;
  const int* ecol = ei + NE;

  char* ws = (char*)d_ws;
  size_t off = 0;
  auto alloc = [&](size_t bytes) {
    void* p = ws + off;
    off = (off + bytes + 255) & ~(size_t)255;
    return p;
  };
  float* alpha = (float*)alloc(NN * 4);
  float* u = (float*)alloc(INC * 4);
  float* v = (float*)alloc(INC * 4);
  float* xsum = (float*)alloc(INC * 4);
  float* xpart = (float*)alloc(64 * INC * 4);
  float* gsum = (float*)alloc(OUTC * 4);
  float* Wc = (float*)alloc(OUTC * INC * 4);
  int* deg = (int*)alloc(NN * 4);
  int* rowstart = (int*)alloc((NN + 1) * 4);
  int* cursor = (int*)alloc(NN * 4);
  int* colbuf = (int*)alloc(NE * 4);
  bf16* g = (bf16*)alloc((size_t)NN * OUTC * 2);
  (void)ws_size; (void)in_sizes; (void)n_in; (void)out_size;

  hipMemsetAsync(deg, 0, NN * 4, stream);
  hipMemsetAsync(cursor, 0, NN * 4, stream);

  k_uv<<<1, 256, 0, stream>>>(W, att_w, u, v);
  k_xsum_part<<<64, 256, 0, stream>>>(x, xpart);
  k_xsum_red<<<1, 256, 0, stream>>>(xpart, xsum);
  k_wc<<<OUTC, 256, 0, stream>>>(lin_w, W, Wc);
  k_gsum<<<OUTC / 256, 256, 0, stream>>>(Wc, xsum, gsum);
  k_alpha<<<NN, 256, 0, stream>>>(x, u, v, alpha);
  k_gemm<<<dim3(OUTC / 64, NN / 64), 256, 0, stream>>>(x, Wc, g);
  k_deg<<<NE / 256, 256, 0, stream>>>(erow, deg);
  k_scan<<<1, 1024, 0, stream>>>(deg, rowstart);
  k_scatter<<<NE / 256, 256, 0, stream>>>(erow, ecol, rowstart, cursor, colbuf);
  k_agg<<<NN, 256, 0, stream>>>(alpha, gsum, g, rowstart, colbuf, out);
}

// Round 2
// 229.194 us; speedup vs baseline: 1.0950x; 1.0950x over previous
//
#include <hip/hip_runtime.h>
#include <hip/hip_bf16.h>

#define NN 8192
#define INC 256
#define OUTC 512
#define NE 262144
#define MAXD 128

typedef __hip_bfloat16 bf16;
typedef short bf16x8 __attribute__((ext_vector_type(8)));
typedef float f32x4 __attribute__((ext_vector_type(4)));

__device__ inline unsigned short f2bu(float f) {
  __hip_bfloat16 b = __float2bfloat16(f);
  return *reinterpret_cast<unsigned short*>(&b);
}

// partial column sums of x; also zero deg/cursor (saves 2 memsets)
__global__ __launch_bounds__(256) void k_xsum_part(const float* __restrict__ x,
                                                   float* __restrict__ xpart,
                                                   int* __restrict__ deg,
                                                   int* __restrict__ cursor) {
  int t = threadIdx.x, b = blockIdx.x;  // 64 blocks
  int gid = b * 256 + t;
  if (gid < NN) deg[gid] = 0;
  else cursor[gid - NN] = 0;
  float acc = 0.f;
  int r0 = b * (NN / 64);
  for (int r = r0; r < r0 + NN / 64; ++r) acc += x[r * INC + t];
  xpart[b * INC + t] = acc;
}

__global__ __launch_bounds__(256) void k_xsum_red(const float* __restrict__ xpart,
                                                  float* __restrict__ xsum) {
  int t = threadIdx.x;
  float acc = 0.f;
  for (int b = 0; b < 64; ++b) acc += xpart[b * INC + t];
  xsum[t] = acc;
}

// Wc = lin_w @ W  [512,256], written as bf16; fused gsum[o] = Wc[o,:].xsum;
// block 0 additionally computes u = att_w@W, v = colsum(W).
__global__ __launch_bounds__(256) void k_wc(const float* __restrict__ lin_w,
                                            const float* __restrict__ W,
                                            const float* __restrict__ att_w,
                                            const float* __restrict__ xsum,
                                            unsigned short* __restrict__ Wcb,
                                            float* __restrict__ gsum,
                                            float* __restrict__ u,
                                            float* __restrict__ v) {
  __shared__ float part[8][4];
  int k = threadIdx.x;
  int l = k & 63, w = k >> 6;
  int o0 = blockIdx.x * 8;
  float acc[8] = {0.f, 0.f, 0.f, 0.f, 0.f, 0.f, 0.f, 0.f};
  float su = 0.f, sv = 0.f;
  bool b0 = (blockIdx.x == 0);
  for (int j = 0; j < OUTC; ++j) {
    float wv = W[j * INC + k];
#pragma unroll
    for (int oo = 0; oo < 8; ++oo) acc[oo] = fmaf(lin_w[(o0 + oo) * OUTC + j], wv, acc[oo]);
    if (b0) { su = fmaf(att_w[j], wv, su); sv += wv; }
  }
  if (b0) { u[k] = su; v[k] = sv; }
#pragma unroll
  for (int oo = 0; oo < 8; ++oo) {
    Wcb[(size_t)(o0 + oo) * INC + k] = f2bu(acc[oo]);
    float r = acc[oo] * xsum[k];
#pragma unroll
    for (int off = 32; off > 0; off >>= 1) r += __shfl_xor(r, off);
    if (l == 0) part[oo][w] = r;
  }
  __syncthreads();
  if (k < 8) gsum[o0 + k] = part[k][0] + part[k][1] + part[k][2] + part[k][3];
}

// x -> bf16
__global__ __launch_bounds__(256) void k_xbf(const float* __restrict__ x,
                                             unsigned short* __restrict__ xb) {
  int idx = (blockIdx.x * 256 + threadIdx.x) * 4;
  float4 vv = *(const float4*)(x + idx);
  ushort4 o;
  o.x = f2bu(vv.x);
  o.y = f2bu(vv.y);
  o.z = f2bu(vv.z);
  o.w = f2bu(vv.w);
  *(ushort4*)(xb + idx) = o;
}

// g = x @ Wc.T  [8192,256]x[512,256]^T -> [8192,512] bf16, MFMA 16x16x32
__global__ __launch_bounds__(256) void k_gemm2(const unsigned short* __restrict__ xb,
                                               const unsigned short* __restrict__ wb,
                                               unsigned short* __restrict__ g) {
  int w = threadIdx.x >> 6, l = threadIdx.x & 63;
  int wm = w >> 1, wn = w & 1;
  int r0 = blockIdx.y * 32 + wm * 16;
  int c0 = blockIdx.x * 32 + wn * 16;
  int lr = l & 15;
  int lk = (l >> 4) * 8;
  const unsigned short* pa = xb + (size_t)(r0 + lr) * INC + lk;
  const unsigned short* pb = wb + (size_t)(c0 + lr) * INC + lk;
  f32x4 acc = {0.f, 0.f, 0.f, 0.f};
#pragma unroll
  for (int k0 = 0; k0 < INC; k0 += 32) {
    bf16x8 a = *(const bf16x8*)(pa + k0);
    bf16x8 b = *(const bf16x8*)(pb + k0);
    acc = __builtin_amdgcn_mfma_f32_16x16x32_bf16(a, b, acc, 0, 0, 0);
  }
  int col = c0 + lr;
  int row0 = r0 + (l >> 4) * 4;
#pragma unroll
  for (int j = 0; j < 4; ++j) g[(size_t)(row0 + j) * OUTC + col] = f2bu(acc[j]);
}

__global__ __launch_bounds__(256) void k_deg(const int* __restrict__ erow, int* __restrict__ deg) {
  int e = blockIdx.x * 256 + threadIdx.x;
  if (e < NE) atomicAdd(&deg[erow[e]], 1);
}

// exclusive scan of deg[8192] -> rowstart[8193]
__global__ __launch_bounds__(1024) void k_scan(const int* __restrict__ deg,
                                               int* __restrict__ rowstart) {
  __shared__ int sums[1024];
  int t = threadIdx.x;
  int base = t * 8;
  int loc[8];
  int s = 0;
#pragma unroll
  for (int j = 0; j < 8; ++j) { loc[j] = s; s += deg[base + j]; }
  sums[t] = s;
  __syncthreads();
  for (int off = 1; off < 1024; off <<= 1) {
    int val = (t >= off) ? sums[t - off] : 0;
    __syncthreads();
    sums[t] += val;
    __syncthreads();
  }
  int prev = (t == 0) ? 0 : sums[t - 1];
#pragma unroll
  for (int j = 0; j < 8; ++j) rowstart[base + j] = prev + loc[j];
  if (t == 1023) rowstart[NN] = sums[1023];
}

__global__ __launch_bounds__(256) void k_scatter(const int* __restrict__ erow,
                                                 const int* __restrict__ ecol,
                                                 const int* __restrict__ rowstart,
                                                 int* __restrict__ cursor,
                                                 int* __restrict__ colbuf) {
  int e = blockIdx.x * 256 + threadIdx.x;
  if (e < NE) {
    int r = erow[e];
    int p = atomicAdd(&cursor[r], 1);
    colbuf[rowstart[r] + p] = ecol[e];
  }
}

// one wave per row: alpha + multiplicities + softmax coefficients
// coeffZ[slot] = (first ? exp(al*m - M) - exp(-M) : 0) / Z ;  rowscale = exp(-M)/Z
__global__ __launch_bounds__(256) void k_coeff(const float* __restrict__ x,
                                               const float* __restrict__ u,
                                               const float* __restrict__ v,
                                               const int* __restrict__ rowstart,
                                               const int* __restrict__ colbuf,
                                               float* __restrict__ coeffZ,
                                               float* __restrict__ rowscale) {
  __shared__ int scols[4][MAXD];
  int w = threadIdx.x >> 6, l = threadIdx.x & 63;
  int i = blockIdx.x * 4 + w;
  // alpha_i = leaky_relu((x_i.u)*(x_i.v))
  float su = 0.f, sv = 0.f;
#pragma unroll
  for (int kk = 0; kk < 4; ++kk) {
    int k = l + kk * 64;
    float xv = x[(size_t)i * INC + k];
    su = fmaf(xv, u[k], su);
    sv = fmaf(xv, v[k], sv);
  }
#pragma unroll
  for (int off = 32; off > 0; off >>= 1) {
    su += __shfl_xor(su, off);
    sv += __shfl_xor(sv, off);
  }
  float a = su * sv;
  float al = a > 0.f ? a : 0.2f * a;

  int s = rowstart[i];
  int d = rowstart[i + 1] - s;
  if (d > MAXD) d = MAXD;
  if (l < d) scols[w][l] = colbuf[s + l];
  int l2 = l + 64;
  if (l2 < d) scols[w][l2] = colbuf[s + l2];
  __syncthreads();
  int c0 = -1, c1 = -1;
  if (l < d) c0 = scols[w][l];
  if (l2 < d) c1 = scols[w][l2];
  int m0 = 0, m1 = 0, f0 = 1, f1 = 1;
  for (int q = 0; q < d; ++q) {
    int cq = scols[w][q];
    if (cq == c0) { m0++; if (q < l) f0 = 0; }
    if (cq == c1) { m1++; if (q < l2) f1 = 0; }
  }
  int mm = m0 > m1 ? m0 : m1;
#pragma unroll
  for (int off = 32; off > 0; off >>= 1) {
    int b = __shfl_xor(mm, off);
    if (b > mm) mm = b;
  }
  float M = (al > 0.f) ? al * (float)mm : 0.f;
  float eMn = expf(-M);
  float se = 0.f;
  int nc = 0;
  float cf0 = 0.f, cf1 = 0.f;
  if (l < d && f0) {
    float e0 = expf(al * (float)m0 - M);
    se += e0; nc++; cf0 = e0 - eMn;
  }
  if (l2 < d && f1) {
    float e1 = expf(al * (float)m1 - M);
    se += e1; nc++; cf1 = e1 - eMn;
  }
#pragma unroll
  for (int off = 32; off > 0; off >>= 1) {
    se += __shfl_xor(se, off);
    nc += __shfl_xor(nc, off);
  }
  float Z = (float)(NN - nc) * eMn + se;
  float invZ = 1.0f / Z;
  if (l < d) coeffZ[s + l] = cf0 * invZ;
  if (l2 < d) coeffZ[s + l2] = cf1 * invZ;
  if (l == 0) rowscale[i] = eMn * invZ;
}

// one wave per row: out[i] = elu( rowscale*gsum + sum_k coeffZ[k]*g[col_k] )
__global__ __launch_bounds__(256) void k_agg2(const float* __restrict__ rowscale,
                                              const float* __restrict__ gsum,
                                              const unsigned short* __restrict__ g,
                                              const int* __restrict__ rowstart,
                                              const int* __restrict__ colbuf,
                                              const float* __restrict__ coeffZ,
                                              float* __restrict__ out) {
  int w = threadIdx.x >> 6, l = threadIdx.x & 63;
  int i = blockIdx.x * 4 + w;
  int s = rowstart[i];
  int d = rowstart[i + 1] - s;
  if (d > MAXD) d = MAXD;
  int c0 = l * 8;
  float rs = rowscale[i];
  float acc[8];
  float4 gs0 = *(const float4*)(gsum + c0);
  float4 gs1 = *(const float4*)(gsum + c0 + 4);
  acc[0] = rs * gs0.x; acc[1] = rs * gs0.y; acc[2] = rs * gs0.z; acc[3] = rs * gs0.w;
  acc[4] = rs * gs1.x; acc[5] = rs * gs1.y; acc[6] = rs * gs1.z; acc[7] = rs * gs1.w;
  for (int k = 0; k < d; ++k) {
    int c = colbuf[s + k];
    float cf = coeffZ[s + k];
    uint4 pv = *(const uint4*)(g + (size_t)c * OUTC + c0);
    acc[0] = fmaf(cf, __uint_as_float(pv.x << 16), acc[0]);
    acc[1] = fmaf(cf, __uint_as_float(pv.x & 0xffff0000u), acc[1]);
    acc[2] = fmaf(cf, __uint_as_float(pv.y << 16), acc[2]);
    acc[3] = fmaf(cf, __uint_as_float(pv.y & 0xffff0000u), acc[3]);
    acc[4] = fmaf(cf, __uint_as_float(pv.z << 16), acc[4]);
    acc[5] = fmaf(cf, __uint_as_float(pv.z & 0xffff0000u), acc[5]);
    acc[6] = fmaf(cf, __uint_as_float(pv.w << 16), acc[6]);
    acc[7] = fmaf(cf, __uint_as_float(pv.w & 0xffff0000u), acc[7]);
  }
  float4 o0, o1;
  o0.x = acc[0] > 0.f ? acc[0] : expm1f(acc[0]);
  o0.y = acc[1] > 0.f ? acc[1] : expm1f(acc[1]);
  o0.z = acc[2] > 0.f ? acc[2] : expm1f(acc[2]);
  o0.w = acc[3] > 0.f ? acc[3] : expm1f(acc[3]);
  o1.x = acc[4] > 0.f ? acc[4] : expm1f(acc[4]);
  o1.y = acc[5] > 0.f ? acc[5] : expm1f(acc[5]);
  o1.z = acc[6] > 0.f ? acc[6] : expm1f(acc[6]);
  o1.w = acc[7] > 0.f ? acc[7] : expm1f(acc[7]);
  float* po = out + (size_t)i * OUTC + c0;
  *(float4*)po = o0;
  *(float4*)(po + 4) = o1;
}

extern "C" void kernel_launch(void* const* d_in, const int* in_sizes, int n_in,
                              void* d_out, int out_size, void* d_ws, size_t ws_size,
                              hipStream_t stream) {
  const float* x = (const float*)d_in[0];
  const int* ei = (const int*)d_in[1];
  const float* W = (const float*)d_in[2];
  const float* att_w = (const float*)d_in[3];
  const float* lin_w = (const float*)d_in[4];
  float* out = (float*)d_out;
  const int* erow = ei;
  const int* ecol = ei + NE;

  char* ws = (char*)d_ws;
  size_t off = 0;
  auto alloc = [&](size_t bytes) {
    void* p = ws + off;
    off = (off + bytes + 255) & ~(size_t)255;
    return p;
  };
  float* u = (float*)alloc(INC * 4);
  float* v = (float*)alloc(INC * 4);
  float* xsum = (float*)alloc(INC * 4);
  float* xpart = (float*)alloc(64 * INC * 4);
  float* gsum = (float*)alloc(OUTC * 4);
  float* rowscale = (float*)alloc(NN * 4);
  unsigned short* Wcb = (unsigned short*)alloc((size_t)OUTC * INC * 2);
  unsigned short* xb = (unsigned short*)alloc((size_t)NN * INC * 2);
  unsigned short* g = (unsigned short*)alloc((size_t)NN * OUTC * 2);
  int* deg = (int*)alloc(NN * 4);
  int* rowstart = (int*)alloc((NN + 1) * 4);
  int* cursor = (int*)alloc(NN * 4);
  int* colbuf = (int*)alloc(NE * 4);
  float* coeffZ = (float*)alloc(NE * 4);
  (void)ws_size; (void)in_sizes; (void)n_in; (void)out_size;

  k_xsum_part<<<64, 256, 0, stream>>>(x, xpart, deg, cursor);
  k_xsum_red<<<1, 256, 0, stream>>>(xpart, xsum);
  k_wc<<<OUTC / 8, 256, 0, stream>>>(lin_w, W, att_w, xsum, Wcb, gsum, u, v);
  k_xbf<<<NN * INC / 1024, 256, 0, stream>>>(x, xb);
  k_gemm2<<<dim3(OUTC / 32, NN / 32), 256, 0, stream>>>(xb, Wcb, g);
  k_deg<<<NE / 256, 256, 0, stream>>>(erow, deg);
  k_scan<<<1, 1024, 0, stream>>>(deg, rowstart);
  k_scatter<<<NE / 256, 256, 0, stream>>>(erow, ecol, rowstart, cursor, colbuf);
  k_coeff<<<NN / 4, 256, 0, stream>>>(x, u, v, rowstart, colbuf, coeffZ, rowscale);
  k_agg2<<<NN / 4, 256, 0, stream>>>(rowscale, gsum, g, rowstart, colbuf, coeffZ, out);
}

// Round 6
// 192.086 us; speedup vs baseline: 1.3066x; 1.1932x over previous
//
#include <hip/hip_runtime.h>
#include <hip/hip_bf16.h>

#define NN 8192
#define INC 256
#define OUTC 512
#define NE 262144
#define MAXD 128

typedef __hip_bfloat16 bf16;
typedef short bf16x8 __attribute__((ext_vector_type(8)));
typedef float f32x4 __attribute__((ext_vector_type(4)));

__device__ inline unsigned short f2bu(float f) {
  __hip_bfloat16 b = __float2bfloat16(f);
  return *reinterpret_cast<unsigned short*>(&b);
}

// partial column sums of x; fused x->bf16 cast; zero deg/cursor (saves memsets)
// 256 blocks, 32 rows each
__global__ __launch_bounds__(256) void k_xsum_part(const float* __restrict__ x,
                                                   float* __restrict__ xpart,
                                                   unsigned short* __restrict__ xb,
                                                   int* __restrict__ deg,
                                                   int* __restrict__ cursor) {
  int t = threadIdx.x, b = blockIdx.x;  // 256 blocks
  int gid = b * 256 + t;
  if (gid < NN) deg[gid] = 0;
  else if (gid < 2 * NN) cursor[gid - NN] = 0;
  float acc = 0.f;
  int r0 = b * (NN / 256);
  for (int r = r0; r < r0 + NN / 256; ++r) {
    float xv = x[r * INC + t];
    acc += xv;
    xb[r * INC + t] = f2bu(xv);
  }
  xpart[b * INC + t] = acc;
}

__global__ __launch_bounds__(256) void k_xsum_red(const float* __restrict__ xpart,
                                                  float* __restrict__ xsum) {
  int t = threadIdx.x;
  float acc = 0.f;
  for (int b = 0; b < 256; ++b) acc += xpart[b * INC + t];
  xsum[t] = acc;
}

// Wc = lin_w @ W  [512,256] -> bf16; fused gsum[o] = Wc[o,:].xsum;
// block 0 additionally computes u = att_w@W, v = colsum(W).
// 256 blocks x 2 outputs: every CU busy.
__global__ __launch_bounds__(256) void k_wc(const float* __restrict__ lin_w,
                                            const float* __restrict__ W,
                                            const float* __restrict__ att_w,
                                            const float* __restrict__ xsum,
                                            unsigned short* __restrict__ Wcb,
                                            float* __restrict__ gsum,
                                            float* __restrict__ u,
                                            float* __restrict__ v) {
  __shared__ float part[2][4];
  int k = threadIdx.x;
  int l = k & 63, w = k >> 6;
  int o0 = blockIdx.x * 2;
  float acc0 = 0.f, acc1 = 0.f, su = 0.f, sv = 0.f;
  bool b0 = (blockIdx.x == 0);
  const float* lw0 = lin_w + (size_t)o0 * OUTC;
  const float* lw1 = lw0 + OUTC;
#pragma unroll 8
  for (int j = 0; j < OUTC; ++j) {
    float wv = W[j * INC + k];
    acc0 = fmaf(lw0[j], wv, acc0);
    acc1 = fmaf(lw1[j], wv, acc1);
    if (b0) { su = fmaf(att_w[j], wv, su); sv += wv; }
  }
  if (b0) { u[k] = su; v[k] = sv; }
#pragma unroll
  for (int oo = 0; oo < 2; ++oo) {
    float a = oo ? acc1 : acc0;
    Wcb[(size_t)(o0 + oo) * INC + k] = f2bu(a);
    float r = a * xsum[k];
#pragma unroll
    for (int off = 32; off > 0; off >>= 1) r += __shfl_xor(r, off);
    if (l == 0) part[oo][w] = r;
  }
  __syncthreads();
  if (k < 2) gsum[o0 + k] = part[k][0] + part[k][1] + part[k][2] + part[k][3];
}

// g = x @ Wc.T  [8192,256]x[512,256]^T -> [8192,512] bf16, MFMA 16x16x32
__global__ __launch_bounds__(256) void k_gemm2(const unsigned short* __restrict__ xb,
                                               const unsigned short* __restrict__ wb,
                                               unsigned short* __restrict__ g) {
  int w = threadIdx.x >> 6, l = threadIdx.x & 63;
  int wm = w >> 1, wn = w & 1;
  int r0 = blockIdx.y * 32 + wm * 16;
  int c0 = blockIdx.x * 32 + wn * 16;
  int lr = l & 15;
  int lk = (l >> 4) * 8;
  const unsigned short* pa = xb + (size_t)(r0 + lr) * INC + lk;
  const unsigned short* pb = wb + (size_t)(c0 + lr) * INC + lk;
  f32x4 acc = {0.f, 0.f, 0.f, 0.f};
#pragma unroll
  for (int k0 = 0; k0 < INC; k0 += 32) {
    bf16x8 a = *(const bf16x8*)(pa + k0);
    bf16x8 b = *(const bf16x8*)(pb + k0);
    acc = __builtin_amdgcn_mfma_f32_16x16x32_bf16(a, b, acc, 0, 0, 0);
  }
  int col = c0 + lr;
  int row0 = r0 + (l >> 4) * 4;
#pragma unroll
  for (int j = 0; j < 4; ++j) g[(size_t)(row0 + j) * OUTC + col] = f2bu(acc[j]);
}

__global__ __launch_bounds__(256) void k_deg(const int* __restrict__ erow, int* __restrict__ deg) {
  int e = blockIdx.x * 256 + threadIdx.x;
  if (e < NE) atomicAdd(&deg[erow[e]], 1);
}

// exclusive scan of deg[8192] -> rowstart[8193]
__global__ __launch_bounds__(1024) void k_scan(const int* __restrict__ deg,
                                               int* __restrict__ rowstart) {
  __shared__ int sums[1024];
  int t = threadIdx.x;
  int base = t * 8;
  int loc[8];
  int s = 0;
#pragma unroll
  for (int j = 0; j < 8; ++j) { loc[j] = s; s += deg[base + j]; }
  sums[t] = s;
  __syncthreads();
  for (int off = 1; off < 1024; off <<= 1) {
    int val = (t >= off) ? sums[t - off] : 0;
    __syncthreads();
    sums[t] += val;
    __syncthreads();
  }
  int prev = (t == 0) ? 0 : sums[t - 1];
#pragma unroll
  for (int j = 0; j < 8; ++j) rowstart[base + j] = prev + loc[j];
  if (t == 1023) rowstart[NN] = sums[1023];
}

__global__ __launch_bounds__(256) void k_scatter(const int* __restrict__ erow,
                                                 const int* __restrict__ ecol,
                                                 const int* __restrict__ rowstart,
                                                 int* __restrict__ cursor,
                                                 int* __restrict__ colbuf) {
  int e = blockIdx.x * 256 + threadIdx.x;
  if (e < NE) {
    int r = erow[e];
    int p = atomicAdd(&cursor[r], 1);
    colbuf[rowstart[r] + p] = ecol[e];
  }
}

// one wave per row: alpha + multiplicities + softmax coefficients
// coeffZ[slot] = (first ? exp(al*m - M) - exp(-M) : 0) / Z ;  rowscale = exp(-M)/Z
__global__ __launch_bounds__(256) void k_coeff(const float* __restrict__ x,
                                               const float* __restrict__ u,
                                               const float* __restrict__ v,
                                               const int* __restrict__ rowstart,
                                               const int* __restrict__ colbuf,
                                               float* __restrict__ coeffZ,
                                               float* __restrict__ rowscale) {
  __shared__ int scols[4][MAXD];
  int w = threadIdx.x >> 6, l = threadIdx.x & 63;
  int i = blockIdx.x * 4 + w;
  float su = 0.f, sv = 0.f;
#pragma unroll
  for (int kk = 0; kk < 4; ++kk) {
    int k = l + kk * 64;
    float xv = x[(size_t)i * INC + k];
    su = fmaf(xv, u[k], su);
    sv = fmaf(xv, v[k], sv);
  }
#pragma unroll
  for (int off = 32; off > 0; off >>= 1) {
    su += __shfl_xor(su, off);
    sv += __shfl_xor(sv, off);
  }
  float a = su * sv;
  float al = a > 0.f ? a : 0.2f * a;

  int s = rowstart[i];
  int d = rowstart[i + 1] - s;
  if (d > MAXD) d = MAXD;
  if (l < d) scols[w][l] = colbuf[s + l];
  int l2 = l + 64;
  if (l2 < d) scols[w][l2] = colbuf[s + l2];
  __syncthreads();
  int c0 = -1, c1 = -1;
  if (l < d) c0 = scols[w][l];
  if (l2 < d) c1 = scols[w][l2];
  int m0 = 0, m1 = 0, f0 = 1, f1 = 1;
  for (int q = 0; q < d; ++q) {
    int cq = scols[w][q];
    if (cq == c0) { m0++; if (q < l) f0 = 0; }
    if (cq == c1) { m1++; if (q < l2) f1 = 0; }
  }
  int mm = m0 > m1 ? m0 : m1;
#pragma unroll
  for (int off = 32; off > 0; off >>= 1) {
    int b = __shfl_xor(mm, off);
    if (b > mm) mm = b;
  }
  float M = (al > 0.f) ? al * (float)mm : 0.f;
  float eMn = expf(-M);
  float se = 0.f;
  int nc = 0;
  float cf0 = 0.f, cf1 = 0.f;
  if (l < d && f0) {
    float e0 = expf(al * (float)m0 - M);
    se += e0; nc++; cf0 = e0 - eMn;
  }
  if (l2 < d && f1) {
    float e1 = expf(al * (float)m1 - M);
    se += e1; nc++; cf1 = e1 - eMn;
  }
#pragma unroll
  for (int off = 32; off > 0; off >>= 1) {
    se += __shfl_xor(se, off);
    nc += __shfl_xor(nc, off);
  }
  float Z = (float)(NN - nc) * eMn + se;
  float invZ = 1.0f / Z;
  if (l < d) coeffZ[s + l] = cf0 * invZ;
  if (l2 < d) coeffZ[s + l2] = cf1 * invZ;
  if (l == 0) rowscale[i] = eMn * invZ;
}

// one wave per row: out[i] = elu( rowscale*gsum + sum_k coeffZ[k]*g[col_k] )
__global__ __launch_bounds__(256) void k_agg2(const float* __restrict__ rowscale,
                                              const float* __restrict__ gsum,
                                              const unsigned short* __restrict__ g,
                                              const int* __restrict__ rowstart,
                                              const int* __restrict__ colbuf,
                                              const float* __restrict__ coeffZ,
                                              float* __restrict__ out) {
  int w = threadIdx.x >> 6, l = threadIdx.x & 63;
  int i = blockIdx.x * 4 + w;
  int s = rowstart[i];
  int d = rowstart[i + 1] - s;
  if (d > MAXD) d = MAXD;
  int c0 = l * 8;
  float rs = rowscale[i];
  float acc[8];
  float4 gs0 = *(const float4*)(gsum + c0);
  float4 gs1 = *(const float4*)(gsum + c0 + 4);
  acc[0] = rs * gs0.x; acc[1] = rs * gs0.y; acc[2] = rs * gs0.z; acc[3] = rs * gs0.w;
  acc[4] = rs * gs1.x; acc[5] = rs * gs1.y; acc[6] = rs * gs1.z; acc[7] = rs * gs1.w;
  for (int k = 0; k < d; ++k) {
    int c = colbuf[s + k];
    float cf = coeffZ[s + k];
    uint4 pv = *(const uint4*)(g + (size_t)c * OUTC + c0);
    acc[0] = fmaf(cf, __uint_as_float(pv.x << 16), acc[0]);
    acc[1] = fmaf(cf, __uint_as_float(pv.x & 0xffff0000u), acc[1]);
    acc[2] = fmaf(cf, __uint_as_float(pv.y << 16), acc[2]);
    acc[3] = fmaf(cf, __uint_as_float(pv.y & 0xffff0000u), acc[3]);
    acc[4] = fmaf(cf, __uint_as_float(pv.z << 16), acc[4]);
    acc[5] = fmaf(cf, __uint_as_float(pv.z & 0xffff0000u), acc[5]);
    acc[6] = fmaf(cf, __uint_as_float(pv.w << 16), acc[6]);
    acc[7] = fmaf(cf, __uint_as_float(pv.w & 0xffff0000u), acc[7]);
  }
  float4 o0, o1;
  o0.x = acc[0] > 0.f ? acc[0] : expm1f(acc[0]);
  o0.y = acc[1] > 0.f ? acc[1] : expm1f(acc[1]);
  o0.z = acc[2] > 0.f ? acc[2] : expm1f(acc[2]);
  o0.w = acc[3] > 0.f ? acc[3] : expm1f(acc[3]);
  o1.x = acc[4] > 0.f ? acc[4] : expm1f(acc[4]);
  o1.y = acc[5] > 0.f ? acc[5] : expm1f(acc[5]);
  o1.z = acc[6] > 0.f ? acc[6] : expm1f(acc[6]);
  o1.w = acc[7] > 0.f ? acc[7] : expm1f(acc[7]);
  float* po = out + (size_t)i * OUTC + c0;
  *(float4*)po = o0;
  *(float4*)(po + 4) = o1;
}

extern "C" void kernel_launch(void* const* d_in, const int* in_sizes, int n_in,
                              void* d_out, int out_size, void* d_ws, size_t ws_size,
                              hipStream_t stream) {
  const float* x = (const float*)d_in[0];
  const int* ei = (const int*)d_in[1];
  const float* W = (const float*)d_in[2];
  const float* att_w = (const float*)d_in[3];
  const float* lin_w = (const float*)d_in[4];
  float* out = (float*)d_out;
  const int* erow = ei;
  const int* ecol = ei + NE;

  char* ws = (char*)d_ws;
  size_t off = 0;
  auto alloc = [&](size_t bytes) {
    void* p = ws + off;
    off = (off + bytes + 255) & ~(size_t)255;
    return p;
  };
  float* u = (float*)alloc(INC * 4);
  float* v = (float*)alloc(INC * 4);
  float* xsum = (float*)alloc(INC * 4);
  float* xpart = (float*)alloc(256 * INC * 4);
  float* gsum = (float*)alloc(OUTC * 4);
  float* rowscale = (float*)alloc(NN * 4);
  unsigned short* Wcb = (unsigned short*)alloc((size_t)OUTC * INC * 2);
  unsigned short* xb = (unsigned short*)alloc((size_t)NN * INC * 2);
  unsigned short* g = (unsigned short*)alloc((size_t)NN * OUTC * 2);
  int* deg = (int*)alloc(NN * 4);
  int* rowstart = (int*)alloc((NN + 1) * 4);
  int* cursor = (int*)alloc(NN * 4);
  int* colbuf = (int*)alloc(NE * 4);
  float* coeffZ = (float*)alloc(NE * 4);
  (void)ws_size; (void)in_sizes; (void)n_in; (void)out_size;

  k_xsum_part<<<256, 256, 0, stream>>>(x, xpart, xb, deg, cursor);
  k_xsum_red<<<1, 256, 0, stream>>>(xpart, xsum);
  k_wc<<<OUTC / 2, 256, 0, stream>>>(lin_w, W, att_w, xsum, Wcb, gsum, u, v);
  k_gemm2<<<dim3(OUTC / 32, NN / 32), 256, 0, stream>>>(xb, Wcb, g);
  k_deg<<<NE / 256, 256, 0, stream>>>(erow, deg);
  k_scan<<<1, 1024, 0, stream>>>(deg, rowstart);
  k_scatter<<<NE / 256, 256, 0, stream>>>(erow, ecol, rowstart, cursor, colbuf);
  k_coeff<<<NN / 4, 256, 0, stream>>>(x, u, v, rowstart, colbuf, coeffZ, rowscale);
  k_agg2<<<NN / 4, 256, 0, stream>>>(rowscale, gsum, g, rowstart, colbuf, coeffZ, out);
}

// Round 7
// 139.317 us; speedup vs baseline: 1.8015x; 1.3788x over previous
//
#include <hip/hip_runtime.h>
#include <hip/hip_bf16.h>

#define NN 8192
#define INC 256
#define OUTC 512
#define NE 262144
#define MAXD 128
#define JC 8
#define JLEN 64  // OUTC / JC

typedef __hip_bfloat16 bf16;
typedef short bf16x8 __attribute__((ext_vector_type(8)));
typedef float f32x4 __attribute__((ext_vector_type(4)));

__device__ inline unsigned short f2bu(float f) {
  __hip_bfloat16 b = __float2bfloat16(f);
  return *reinterpret_cast<unsigned short*>(&b);
}

// partial column sums of x (transposed out); fused x->bf16; zero deg/cursor.
// 256 blocks, 32 rows each. xpartT[k][b]
__global__ __launch_bounds__(256) void k_xsum_part(const float* __restrict__ x,
                                                   float* __restrict__ xpartT,
                                                   unsigned short* __restrict__ xb,
                                                   int* __restrict__ deg,
                                                   int* __restrict__ cursor) {
  int t = threadIdx.x, b = blockIdx.x;  // 256 blocks
  int gid = b * 256 + t;
  if (gid < NN) deg[gid] = 0;
  else if (gid < 2 * NN) cursor[gid - NN] = 0;
  float acc = 0.f;
  int r0 = b * (NN / 256);
  for (int r = r0; r < r0 + NN / 256; ++r) {
    float xv = x[r * INC + t];
    acc += xv;
    xb[r * INC + t] = f2bu(xv);
  }
  xpartT[t * 256 + b] = acc;
}

// 256 blocks: block k reduces xpartT[k][0..255] (coalesced)
__global__ __launch_bounds__(256) void k_xsum_red(const float* __restrict__ xpartT,
                                                  float* __restrict__ xsum) {
  __shared__ float sred[4];
  int k = blockIdx.x, t = threadIdx.x;
  int l = t & 63, w = t >> 6;
  float r = xpartT[k * 256 + t];
#pragma unroll
  for (int off = 32; off > 0; off >>= 1) r += __shfl_xor(r, off);
  if (l == 0) sred[w] = r;
  __syncthreads();
  if (t == 0) xsum[k] = sred[0] + sred[1] + sred[2] + sred[3];
}

// Stage 1 of Wc = lin_w @ W: j-chunked partials.
// grid (OUTC/4, JC) = (128, 8); 256 threads; 64-j chain per block.
__global__ __launch_bounds__(256) void k_wc_part(const float* __restrict__ lin_w,
                                                 const float* __restrict__ W,
                                                 const float* __restrict__ att_w,
                                                 float* __restrict__ part,
                                                 float* __restrict__ uvpart) {
  int k = threadIdx.x;
  int o0 = blockIdx.x * 4;
  int jc = blockIdx.y;
  int j0 = jc * JLEN;
  float a0 = 0.f, a1 = 0.f, a2 = 0.f, a3 = 0.f, su = 0.f, sv = 0.f;
  bool b0 = (blockIdx.x == 0);
  const float* lw0 = lin_w + (size_t)(o0 + 0) * OUTC + j0;
  const float* lw1 = lin_w + (size_t)(o0 + 1) * OUTC + j0;
  const float* lw2 = lin_w + (size_t)(o0 + 2) * OUTC + j0;
  const float* lw3 = lin_w + (size_t)(o0 + 3) * OUTC + j0;
#pragma unroll 8
  for (int jj = 0; jj < JLEN; ++jj) {
    float wv = W[(j0 + jj) * INC + k];
    a0 = fmaf(lw0[jj], wv, a0);
    a1 = fmaf(lw1[jj], wv, a1);
    a2 = fmaf(lw2[jj], wv, a2);
    a3 = fmaf(lw3[jj], wv, a3);
    if (b0) { su = fmaf(att_w[j0 + jj], wv, su); sv += wv; }
  }
  float* pb = part + ((size_t)jc * OUTC + o0) * INC + k;
  pb[0] = a0;
  pb[INC] = a1;
  pb[2 * INC] = a2;
  pb[3 * INC] = a3;
  if (b0) {
    uvpart[(jc * 2 + 0) * INC + k] = su;
    uvpart[(jc * 2 + 1) * INC + k] = sv;
  }
}

// Stage 2: reduce 8 partials -> Wcb bf16, gsum; block 0 also u,v.
// 128 blocks x 4 outputs.
__global__ __launch_bounds__(256) void k_wc_red(const float* __restrict__ part,
                                                const float* __restrict__ uvpart,
                                                const float* __restrict__ xsum,
                                                unsigned short* __restrict__ Wcb,
                                                float* __restrict__ gsum,
                                                float* __restrict__ u,
                                                float* __restrict__ v) {
  __shared__ float sred[4][4];
  int k = threadIdx.x;
  int l = k & 63, w = k >> 6;
  int o0 = blockIdx.x * 4;
#pragma unroll
  for (int oo = 0; oo < 4; ++oo) {
    float s = 0.f;
#pragma unroll
    for (int jc = 0; jc < JC; ++jc)
      s += part[((size_t)jc * OUTC + o0 + oo) * INC + k];
    Wcb[(size_t)(o0 + oo) * INC + k] = f2bu(s);
    float r = s * xsum[k];
#pragma unroll
    for (int off = 32; off > 0; off >>= 1) r += __shfl_xor(r, off);
    if (l == 0) sred[oo][w] = r;
  }
  __syncthreads();
  if (k < 4) gsum[o0 + k] = sred[k][0] + sred[k][1] + sred[k][2] + sred[k][3];
  if (blockIdx.x == 0) {
    float su = 0.f, sv = 0.f;
#pragma unroll
    for (int jc = 0; jc < JC; ++jc) {
      su += uvpart[(jc * 2 + 0) * INC + k];
      sv += uvpart[(jc * 2 + 1) * INC + k];
    }
    u[k] = su;
    v[k] = sv;
  }
}

// g = x @ Wc.T  [8192,256]x[512,256]^T -> [8192,512] bf16, MFMA 16x16x32
__global__ __launch_bounds__(256) void k_gemm2(const unsigned short* __restrict__ xb,
                                               const unsigned short* __restrict__ wb,
                                               unsigned short* __restrict__ g) {
  int w = threadIdx.x >> 6, l = threadIdx.x & 63;
  int wm = w >> 1, wn = w & 1;
  int r0 = blockIdx.y * 32 + wm * 16;
  int c0 = blockIdx.x * 32 + wn * 16;
  int lr = l & 15;
  int lk = (l >> 4) * 8;
  const unsigned short* pa = xb + (size_t)(r0 + lr) * INC + lk;
  const unsigned short* pb = wb + (size_t)(c0 + lr) * INC + lk;
  f32x4 acc = {0.f, 0.f, 0.f, 0.f};
#pragma unroll
  for (int k0 = 0; k0 < INC; k0 += 32) {
    bf16x8 a = *(const bf16x8*)(pa + k0);
    bf16x8 b = *(const bf16x8*)(pb + k0);
    acc = __builtin_amdgcn_mfma_f32_16x16x32_bf16(a, b, acc, 0, 0, 0);
  }
  int col = c0 + lr;
  int row0 = r0 + (l >> 4) * 4;
#pragma unroll
  for (int j = 0; j < 4; ++j) g[(size_t)(row0 + j) * OUTC + col] = f2bu(acc[j]);
}

__global__ __launch_bounds__(256) void k_deg(const int* __restrict__ erow, int* __restrict__ deg) {
  int e = blockIdx.x * 256 + threadIdx.x;
  if (e < NE) atomicAdd(&deg[erow[e]], 1);
}

// exclusive scan of deg[8192] -> rowstart[8193]
__global__ __launch_bounds__(1024) void k_scan(const int* __restrict__ deg,
                                               int* __restrict__ rowstart) {
  __shared__ int sums[1024];
  int t = threadIdx.x;
  int base = t * 8;
  int loc[8];
  int s = 0;
#pragma unroll
  for (int j = 0; j < 8; ++j) { loc[j] = s; s += deg[base + j]; }
  sums[t] = s;
  __syncthreads();
  for (int off = 1; off < 1024; off <<= 1) {
    int val = (t >= off) ? sums[t - off] : 0;
    __syncthreads();
    sums[t] += val;
    __syncthreads();
  }
  int prev = (t == 0) ? 0 : sums[t - 1];
#pragma unroll
  for (int j = 0; j < 8; ++j) rowstart[base + j] = prev + loc[j];
  if (t == 1023) rowstart[NN] = sums[1023];
}

__global__ __launch_bounds__(256) void k_scatter(const int* __restrict__ erow,
                                                 const int* __restrict__ ecol,
                                                 const int* __restrict__ rowstart,
                                                 int* __restrict__ cursor,
                                                 int* __restrict__ colbuf) {
  int e = blockIdx.x * 256 + threadIdx.x;
  if (e < NE) {
    int r = erow[e];
    int p = atomicAdd(&cursor[r], 1);
    colbuf[rowstart[r] + p] = ecol[e];
  }
}

// one wave per row: alpha + multiplicities + softmax coefficients
// coeffZ[slot] = (first ? exp(al*m - M) - exp(-M) : 0) / Z ;  rowscale = exp(-M)/Z
__global__ __launch_bounds__(256) void k_coeff(const float* __restrict__ x,
                                               const float* __restrict__ u,
                                               const float* __restrict__ v,
                                               const int* __restrict__ rowstart,
                                               const int* __restrict__ colbuf,
                                               float* __restrict__ coeffZ,
                                               float* __restrict__ rowscale) {
  __shared__ int scols[4][MAXD];
  int w = threadIdx.x >> 6, l = threadIdx.x & 63;
  int i = blockIdx.x * 4 + w;
  float su = 0.f, sv = 0.f;
#pragma unroll
  for (int kk = 0; kk < 4; ++kk) {
    int k = l + kk * 64;
    float xv = x[(size_t)i * INC + k];
    su = fmaf(xv, u[k], su);
    sv = fmaf(xv, v[k], sv);
  }
#pragma unroll
  for (int off = 32; off > 0; off >>= 1) {
    su += __shfl_xor(su, off);
    sv += __shfl_xor(sv, off);
  }
  float a = su * sv;
  float al = a > 0.f ? a : 0.2f * a;

  int s = rowstart[i];
  int d = rowstart[i + 1] - s;
  if (d > MAXD) d = MAXD;
  if (l < d) scols[w][l] = colbuf[s + l];
  int l2 = l + 64;
  if (l2 < d) scols[w][l2] = colbuf[s + l2];
  __syncthreads();
  int c0 = -1, c1 = -1;
  if (l < d) c0 = scols[w][l];
  if (l2 < d) c1 = scols[w][l2];
  int m0 = 0, m1 = 0, f0 = 1, f1 = 1;
  for (int q = 0; q < d; ++q) {
    int cq = scols[w][q];
    if (cq == c0) { m0++; if (q < l) f0 = 0; }
    if (cq == c1) { m1++; if (q < l2) f1 = 0; }
  }
  int mm = m0 > m1 ? m0 : m1;
#pragma unroll
  for (int off = 32; off > 0; off >>= 1) {
    int b = __shfl_xor(mm, off);
    if (b > mm) mm = b;
  }
  float M = (al > 0.f) ? al * (float)mm : 0.f;
  float eMn = expf(-M);
  float se = 0.f;
  int nc = 0;
  float cf0 = 0.f, cf1 = 0.f;
  if (l < d && f0) {
    float e0 = expf(al * (float)m0 - M);
    se += e0; nc++; cf0 = e0 - eMn;
  }
  if (l2 < d && f1) {
    float e1 = expf(al * (float)m1 - M);
    se += e1; nc++; cf1 = e1 - eMn;
  }
#pragma unroll
  for (int off = 32; off > 0; off >>= 1) {
    se += __shfl_xor(se, off);
    nc += __shfl_xor(nc, off);
  }
  float Z = (float)(NN - nc) * eMn + se;
  float invZ = 1.0f / Z;
  if (l < d) coeffZ[s + l] = cf0 * invZ;
  if (l2 < d) coeffZ[s + l2] = cf1 * invZ;
  if (l == 0) rowscale[i] = eMn * invZ;
}

// one wave per row: out[i] = elu( rowscale*gsum + sum_k coeffZ[k]*g[col_k] )
__global__ __launch_bounds__(256) void k_agg2(const float* __restrict__ rowscale,
                                              const float* __restrict__ gsum,
                                              const unsigned short* __restrict__ g,
                                              const int* __restrict__ rowstart,
                                              const int* __restrict__ colbuf,
                                              const float* __restrict__ coeffZ,
                                              float* __restrict__ out) {
  int w = threadIdx.x >> 6, l = threadIdx.x & 63;
  int i = blockIdx.x * 4 + w;
  int s = rowstart[i];
  int d = rowstart[i + 1] - s;
  if (d > MAXD) d = MAXD;
  int c0 = l * 8;
  float rs = rowscale[i];
  float acc[8];
  float4 gs0 = *(const float4*)(gsum + c0);
  float4 gs1 = *(const float4*)(gsum + c0 + 4);
  acc[0] = rs * gs0.x; acc[1] = rs * gs0.y; acc[2] = rs * gs0.z; acc[3] = rs * gs0.w;
  acc[4] = rs * gs1.x; acc[5] = rs * gs1.y; acc[6] = rs * gs1.z; acc[7] = rs * gs1.w;
  for (int k = 0; k < d; ++k) {
    int c = colbuf[s + k];
    float cf = coeffZ[s + k];
    uint4 pv = *(const uint4*)(g + (size_t)c * OUTC + c0);
    acc[0] = fmaf(cf, __uint_as_float(pv.x << 16), acc[0]);
    acc[1] = fmaf(cf, __uint_as_float(pv.x & 0xffff0000u), acc[1]);
    acc[2] = fmaf(cf, __uint_as_float(pv.y << 16), acc[2]);
    acc[3] = fmaf(cf, __uint_as_float(pv.y & 0xffff0000u), acc[3]);
    acc[4] = fmaf(cf, __uint_as_float(pv.z << 16), acc[4]);
    acc[5] = fmaf(cf, __uint_as_float(pv.z & 0xffff0000u), acc[5]);
    acc[6] = fmaf(cf, __uint_as_float(pv.w << 16), acc[6]);
    acc[7] = fmaf(cf, __uint_as_float(pv.w & 0xffff0000u), acc[7]);
  }
  float4 o0, o1;
  o0.x = acc[0] > 0.f ? acc[0] : expm1f(acc[0]);
  o0.y = acc[1] > 0.f ? acc[1] : expm1f(acc[1]);
  o0.z = acc[2] > 0.f ? acc[2] : expm1f(acc[2]);
  o0.w = acc[3] > 0.f ? acc[3] : expm1f(acc[3]);
  o1.x = acc[4] > 0.f ? acc[4] : expm1f(acc[4]);
  o1.y = acc[5] > 0.f ? acc[5] : expm1f(acc[5]);
  o1.z = acc[6] > 0.f ? acc[6] : expm1f(acc[6]);
  o1.w = acc[7] > 0.f ? acc[7] : expm1f(acc[7]);
  float* po = out + (size_t)i * OUTC + c0;
  *(float4*)po = o0;
  *(float4*)(po + 4) = o1;
}

extern "C" void kernel_launch(void* const* d_in, const int* in_sizes, int n_in,
                              void* d_out, int out_size, void* d_ws, size_t ws_size,
                              hipStream_t stream) {
  const float* x = (const float*)d_in[0];
  const int* ei = (const int*)d_in[1];
  const float* W = (const float*)d_in[2];
  const float* att_w = (const float*)d_in[3];
  const float* lin_w = (const float*)d_in[4];
  float* out = (float*)d_out;
  const int* erow = ei;
  const int* ecol = ei + NE;

  char* ws = (char*)d_ws;
  size_t off = 0;
  auto alloc = [&](size_t bytes) {
    void* p = ws + off;
    off = (off + bytes + 255) & ~(size_t)255;
    return p;
  };
  float* u = (float*)alloc(INC * 4);
  float* v = (float*)alloc(INC * 4);
  float* xsum = (float*)alloc(INC * 4);
  float* xpartT = (float*)alloc(INC * 256 * 4);
  float* gsum = (float*)alloc(OUTC * 4);
  float* rowscale = (float*)alloc(NN * 4);
  float* part = (float*)alloc((size_t)JC * OUTC * INC * 4);
  float* uvpart = (float*)alloc(JC * 2 * INC * 4);
  unsigned short* Wcb = (unsigned short*)alloc((size_t)OUTC * INC * 2);
  unsigned short* xb = (unsigned short*)alloc((size_t)NN * INC * 2);
  unsigned short* g = (unsigned short*)alloc((size_t)NN * OUTC * 2);
  int* deg = (int*)alloc(NN * 4);
  int* rowstart = (int*)alloc((NN + 1) * 4);
  int* cursor = (int*)alloc(NN * 4);
  int* colbuf = (int*)alloc(NE * 4);
  float* coeffZ = (float*)alloc(NE * 4);
  (void)ws_size; (void)in_sizes; (void)n_in; (void)out_size;

  k_xsum_part<<<256, 256, 0, stream>>>(x, xpartT, xb, deg, cursor);
  k_xsum_red<<<INC, 256, 0, stream>>>(xpartT, xsum);
  k_wc_part<<<dim3(OUTC / 4, JC), 256, 0, stream>>>(lin_w, W, att_w, part, uvpart);
  k_wc_red<<<OUTC / 4, 256, 0, stream>>>(part, uvpart, xsum, Wcb, gsum, u, v);
  k_gemm2<<<dim3(OUTC / 32, NN / 32), 256, 0, stream>>>(xb, Wcb, g);
  k_deg<<<NE / 256, 256, 0, stream>>>(erow, deg);
  k_scan<<<1, 1024, 0, stream>>>(deg, rowstart);
  k_scatter<<<NE / 256, 256, 0, stream>>>(erow, ecol, rowstart, cursor, colbuf);
  k_coeff<<<NN / 4, 256, 0, stream>>>(x, u, v, rowstart, colbuf, coeffZ, rowscale);
  k_agg2<<<NN / 4, 256, 0, stream>>>(rowscale, gsum, g, rowstart, colbuf, coeffZ, out);
}

// Round 8
// 109.728 us; speedup vs baseline: 2.2873x; 1.2697x over previous
//
#include <hip/hip_runtime.h>
#include <hip/hip_bf16.h>

#define NN 8192
#define INC 256
#define OUTC 512
#define NE 262144
#define MAXD 128
#define JC 8
#define JLEN 64  // OUTC / JC

typedef __hip_bfloat16 bf16;
typedef short bf16x8 __attribute__((ext_vector_type(8)));
typedef float f32x4 __attribute__((ext_vector_type(4)));
typedef float f32x16 __attribute__((ext_vector_type(16)));

__device__ inline unsigned short f2bu(float f) {
  __hip_bfloat16 b = __float2bfloat16(f);
  return *reinterpret_cast<unsigned short*>(&b);
}

// partial column sums of x (transposed out); fused x->bf16; zero deg/cursor.
// 256 blocks, 32 rows each. xpartT[k][b]
__global__ __launch_bounds__(256) void k_xsum_part(const float* __restrict__ x,
                                                   float* __restrict__ xpartT,
                                                   unsigned short* __restrict__ xb,
                                                   int* __restrict__ deg,
                                                   int* __restrict__ cursor) {
  int t = threadIdx.x, b = blockIdx.x;  // 256 blocks
  int gid = b * 256 + t;
  if (gid < NN) deg[gid] = 0;
  else if (gid < 2 * NN) cursor[gid - NN] = 0;
  float acc = 0.f;
  int r0 = b * (NN / 256);
  for (int r = r0; r < r0 + NN / 256; ++r) {
    float xv = x[r * INC + t];
    acc += xv;
    xb[r * INC + t] = f2bu(xv);
  }
  xpartT[t * 256 + b] = acc;
}

// 256 blocks: block k reduces xpartT[k][0..255]; fused edge-degree atomics.
__global__ __launch_bounds__(256) void k_xsum_red(const float* __restrict__ xpartT,
                                                  float* __restrict__ xsum,
                                                  const int* __restrict__ erow,
                                                  int* __restrict__ deg) {
  __shared__ float sred[4];
  int k = blockIdx.x, t = threadIdx.x;
  int l = t & 63, w = t >> 6;
  float r = xpartT[k * 256 + t];
#pragma unroll
  for (int off = 32; off > 0; off >>= 1) r += __shfl_xor(r, off);
  if (l == 0) sred[w] = r;
  // degree atomics: 65536 threads x 4 edges
  int e0 = (k * 256 + t) * 4;
  int4 ev = *(const int4*)(erow + e0);
  atomicAdd(&deg[ev.x], 1);
  atomicAdd(&deg[ev.y], 1);
  atomicAdd(&deg[ev.z], 1);
  atomicAdd(&deg[ev.w], 1);
  __syncthreads();
  if (t == 0) xsum[k] = sred[0] + sred[1] + sred[2] + sred[3];
}

// Stage 1 of Wc = lin_w @ W: j-chunked partials.
// grid (OUTC/4, JC) = (128, 8); 256 threads; 64-j chain per block.
__global__ __launch_bounds__(256) void k_wc_part(const float* __restrict__ lin_w,
                                                 const float* __restrict__ W,
                                                 const float* __restrict__ att_w,
                                                 float* __restrict__ part,
                                                 float* __restrict__ uvpart) {
  int k = threadIdx.x;
  int o0 = blockIdx.x * 4;
  int jc = blockIdx.y;
  int j0 = jc * JLEN;
  float a0 = 0.f, a1 = 0.f, a2 = 0.f, a3 = 0.f, su = 0.f, sv = 0.f;
  bool b0 = (blockIdx.x == 0);
  const float* lw0 = lin_w + (size_t)(o0 + 0) * OUTC + j0;
  const float* lw1 = lin_w + (size_t)(o0 + 1) * OUTC + j0;
  const float* lw2 = lin_w + (size_t)(o0 + 2) * OUTC + j0;
  const float* lw3 = lin_w + (size_t)(o0 + 3) * OUTC + j0;
#pragma unroll 8
  for (int jj = 0; jj < JLEN; ++jj) {
    float wv = W[(j0 + jj) * INC + k];
    a0 = fmaf(lw0[jj], wv, a0);
    a1 = fmaf(lw1[jj], wv, a1);
    a2 = fmaf(lw2[jj], wv, a2);
    a3 = fmaf(lw3[jj], wv, a3);
    if (b0) { su = fmaf(att_w[j0 + jj], wv, su); sv += wv; }
  }
  float* pb = part + ((size_t)jc * OUTC + o0) * INC + k;
  pb[0] = a0;
  pb[INC] = a1;
  pb[2 * INC] = a2;
  pb[3 * INC] = a3;
  if (b0) {
    uvpart[(jc * 2 + 0) * INC + k] = su;
    uvpart[(jc * 2 + 1) * INC + k] = sv;
  }
}

// Stage 2: reduce 8 partials -> Wcb bf16, gsum; block 0 also u,v.
// 128 blocks x 4 outputs.
__global__ __launch_bounds__(256) void k_wc_red(const float* __restrict__ part,
                                                const float* __restrict__ uvpart,
                                                const float* __restrict__ xsum,
                                                unsigned short* __restrict__ Wcb,
                                                float* __restrict__ gsum,
                                                float* __restrict__ u,
                                                float* __restrict__ v) {
  __shared__ float sred[4][4];
  int k = threadIdx.x;
  int l = k & 63, w = k >> 6;
  int o0 = blockIdx.x * 4;
#pragma unroll
  for (int oo = 0; oo < 4; ++oo) {
    float s = 0.f;
#pragma unroll
    for (int jc = 0; jc < JC; ++jc)
      s += part[((size_t)jc * OUTC + o0 + oo) * INC + k];
    Wcb[(size_t)(o0 + oo) * INC + k] = f2bu(s);
    float r = s * xsum[k];
#pragma unroll
    for (int off = 32; off > 0; off >>= 1) r += __shfl_xor(r, off);
    if (l == 0) sred[oo][w] = r;
  }
  __syncthreads();
  if (k < 4) gsum[o0 + k] = sred[k][0] + sred[k][1] + sred[k][2] + sred[k][3];
  if (blockIdx.x == 0) {
    float su = 0.f, sv = 0.f;
#pragma unroll
    for (int jc = 0; jc < JC; ++jc) {
      su += uvpart[(jc * 2 + 0) * INC + k];
      sv += uvpart[(jc * 2 + 1) * INC + k];
    }
    u[k] = su;
    v[k] = sv;
  }
}

// g = x @ Wc.T -> [8192,512] bf16. MFMA 32x32x16, 64x64 block tile, 2x2 waves.
__global__ __launch_bounds__(256) void k_gemm3(const unsigned short* __restrict__ xb,
                                               const unsigned short* __restrict__ wb,
                                               unsigned short* __restrict__ g) {
  int w = threadIdx.x >> 6, l = threadIdx.x & 63;
  int wm = w >> 1, wn = w & 1;
  int r0 = blockIdx.y * 64 + wm * 32;
  int c0 = blockIdx.x * 64 + wn * 32;
  int lr = l & 31;
  int lk = (l >> 5) * 8;
  const unsigned short* pa = xb + (size_t)(r0 + lr) * INC + lk;
  const unsigned short* pb = wb + (size_t)(c0 + lr) * INC + lk;
  f32x16 acc = {};
#pragma unroll
  for (int k0 = 0; k0 < INC; k0 += 16) {
    bf16x8 a = *(const bf16x8*)(pa + k0);
    bf16x8 b = *(const bf16x8*)(pb + k0);
    acc = __builtin_amdgcn_mfma_f32_32x32x16_bf16(a, b, acc, 0, 0, 0);
  }
  // C/D: col = lane&31, row = (reg&3) + 8*(reg>>2) + 4*(lane>>5)
  int col = c0 + lr;
  int rbase = r0 + 4 * (l >> 5);
#pragma unroll
  for (int reg = 0; reg < 16; ++reg) {
    int row = rbase + (reg & 3) + 8 * (reg >> 2);
    g[(size_t)row * OUTC + col] = f2bu(acc[reg]);
  }
}

// exclusive scan of deg[8192] -> rowstart[8193]
__global__ __launch_bounds__(1024) void k_scan(const int* __restrict__ deg,
                                               int* __restrict__ rowstart) {
  __shared__ int sums[1024];
  int t = threadIdx.x;
  int base = t * 8;
  int loc[8];
  int s = 0;
#pragma unroll
  for (int j = 0; j < 8; ++j) { loc[j] = s; s += deg[base + j]; }
  sums[t] = s;
  __syncthreads();
  for (int off = 1; off < 1024; off <<= 1) {
    int val = (t >= off) ? sums[t - off] : 0;
    __syncthreads();
    sums[t] += val;
    __syncthreads();
  }
  int prev = (t == 0) ? 0 : sums[t - 1];
#pragma unroll
  for (int j = 0; j < 8; ++j) rowstart[base + j] = prev + loc[j];
  if (t == 1023) rowstart[NN] = sums[1023];
}

__global__ __launch_bounds__(256) void k_scatter(const int* __restrict__ erow,
                                                 const int* __restrict__ ecol,
                                                 const int* __restrict__ rowstart,
                                                 int* __restrict__ cursor,
                                                 int* __restrict__ colbuf) {
  int e = blockIdx.x * 256 + threadIdx.x;
  if (e < NE) {
    int r = erow[e];
    int p = atomicAdd(&cursor[r], 1);
    colbuf[rowstart[r] + p] = ecol[e];
  }
}

// FUSED coeff+aggregate: one wave per row.
// Phase A (lanes = edge slots): alpha, multiplicities, softmax coeffs -> LDS.
// Phase B (lanes = channel octets): out[i] = elu(rs*gsum + sum_k cf[k]*g[col_k]).
__global__ __launch_bounds__(256) void k_sagg(const float* __restrict__ x,
                                              const float* __restrict__ u,
                                              const float* __restrict__ v,
                                              const float* __restrict__ gsum,
                                              const unsigned short* __restrict__ g,
                                              const int* __restrict__ rowstart,
                                              const int* __restrict__ colbuf,
                                              float* __restrict__ out) {
  __shared__ int scols[4][MAXD];
  __shared__ float scoef[4][MAXD];
  int w = threadIdx.x >> 6, l = threadIdx.x & 63;
  int i = blockIdx.x * 4 + w;

  // alpha_i = leaky_relu((x_i.u)*(x_i.v))
  float su = 0.f, sv = 0.f;
#pragma unroll
  for (int kk = 0; kk < 4; ++kk) {
    int k = l + kk * 64;
    float xv = x[(size_t)i * INC + k];
    su = fmaf(xv, u[k], su);
    sv = fmaf(xv, v[k], sv);
  }
#pragma unroll
  for (int off = 32; off > 0; off >>= 1) {
    su += __shfl_xor(su, off);
    sv += __shfl_xor(sv, off);
  }
  float a = su * sv;
  float al = a > 0.f ? a : 0.2f * a;

  int s = rowstart[i];
  int d = rowstart[i + 1] - s;
  if (d > MAXD) d = MAXD;
  if (l < d) scols[w][l] = colbuf[s + l];
  int l2 = l + 64;
  if (l2 < d) scols[w][l2] = colbuf[s + l2];
  __syncthreads();
  int c0s = -1, c1s = -2;
  if (l < d) c0s = scols[w][l];
  if (l2 < d) c1s = scols[w][l2];
  int m0 = 0, m1 = 0, f0 = 1, f1 = 1;
  for (int q = 0; q < d; ++q) {
    int cq = scols[w][q];
    if (cq == c0s) { m0++; if (q < l) f0 = 0; }
    if (cq == c1s) { m1++; if (q < l2) f1 = 0; }
  }
  int mm = m0 > m1 ? m0 : m1;
#pragma unroll
  for (int off = 32; off > 0; off >>= 1) {
    int b = __shfl_xor(mm, off);
    if (b > mm) mm = b;
  }
  float M = (al > 0.f) ? al * (float)mm : 0.f;
  float eMn = expf(-M);
  float se = 0.f;
  int nc = 0;
  float cf0 = 0.f, cf1 = 0.f;
  if (l < d && f0) {
    float e0 = expf(al * (float)m0 - M);
    se += e0; nc++; cf0 = e0 - eMn;
  }
  if (l2 < d && f1) {
    float e1 = expf(al * (float)m1 - M);
    se += e1; nc++; cf1 = e1 - eMn;
  }
#pragma unroll
  for (int off = 32; off > 0; off >>= 1) {
    se += __shfl_xor(se, off);
    nc += __shfl_xor(nc, off);
  }
  float Z = (float)(NN - nc) * eMn + se;
  float invZ = 1.0f / Z;
  if (l < d) scoef[w][l] = cf0 * invZ;
  if (l2 < d) scoef[w][l2] = cf1 * invZ;
  float rs = eMn * invZ;

  // Phase B: gather. lane owns channels [8l, 8l+8)
  int c0 = l * 8;
  float acc[8];
  float4 gs0 = *(const float4*)(gsum + c0);
  float4 gs1 = *(const float4*)(gsum + c0 + 4);
  acc[0] = rs * gs0.x; acc[1] = rs * gs0.y; acc[2] = rs * gs0.z; acc[3] = rs * gs0.w;
  acc[4] = rs * gs1.x; acc[5] = rs * gs1.y; acc[6] = rs * gs1.z; acc[7] = rs * gs1.w;
  for (int k = 0; k < d; ++k) {
    int c = scols[w][k];
    float cf = scoef[w][k];
    uint4 pv = *(const uint4*)(g + (size_t)c * OUTC + c0);
    acc[0] = fmaf(cf, __uint_as_float(pv.x << 16), acc[0]);
    acc[1] = fmaf(cf, __uint_as_float(pv.x & 0xffff0000u), acc[1]);
    acc[2] = fmaf(cf, __uint_as_float(pv.y << 16), acc[2]);
    acc[3] = fmaf(cf, __uint_as_float(pv.y & 0xffff0000u), acc[3]);
    acc[4] = fmaf(cf, __uint_as_float(pv.z << 16), acc[4]);
    acc[5] = fmaf(cf, __uint_as_float(pv.z & 0xffff0000u), acc[5]);
    acc[6] = fmaf(cf, __uint_as_float(pv.w << 16), acc[6]);
    acc[7] = fmaf(cf, __uint_as_float(pv.w & 0xffff0000u), acc[7]);
  }
  float4 o0, o1;
  o0.x = acc[0] > 0.f ? acc[0] : expm1f(acc[0]);
  o0.y = acc[1] > 0.f ? acc[1] : expm1f(acc[1]);
  o0.z = acc[2] > 0.f ? acc[2] : expm1f(acc[2]);
  o0.w = acc[3] > 0.f ? acc[3] : expm1f(acc[3]);
  o1.x = acc[4] > 0.f ? acc[4] : expm1f(acc[4]);
  o1.y = acc[5] > 0.f ? acc[5] : expm1f(acc[5]);
  o1.z = acc[6] > 0.f ? acc[6] : expm1f(acc[6]);
  o1.w = acc[7] > 0.f ? acc[7] : expm1f(acc[7]);
  float* po = out + (size_t)i * OUTC + c0;
  *(float4*)po = o0;
  *(float4*)(po + 4) = o1;
}

extern "C" void kernel_launch(void* const* d_in, const int* in_sizes, int n_in,
                              void* d_out, int out_size, void* d_ws, size_t ws_size,
                              hipStream_t stream) {
  const float* x = (const float*)d_in[0];
  const int* ei = (const int*)d_in[1];
  const float* W = (const float*)d_in[2];
  const float* att_w = (const float*)d_in[3];
  const float* lin_w = (const float*)d_in[4];
  float* out = (float*)d_out;
  const int* erow = ei;
  const int* ecol = ei + NE;

  char* ws = (char*)d_ws;
  size_t off = 0;
  auto alloc = [&](size_t bytes) {
    void* p = ws + off;
    off = (off + bytes + 255) & ~(size_t)255;
    return p;
  };
  float* u = (float*)alloc(INC * 4);
  float* v = (float*)alloc(INC * 4);
  float* xsum = (float*)alloc(INC * 4);
  float* xpartT = (float*)alloc(INC * 256 * 4);
  float* gsum = (float*)alloc(OUTC * 4);
  float* part = (float*)alloc((size_t)JC * OUTC * INC * 4);
  float* uvpart = (float*)alloc(JC * 2 * INC * 4);
  unsigned short* Wcb = (unsigned short*)alloc((size_t)OUTC * INC * 2);
  unsigned short* xb = (unsigned short*)alloc((size_t)NN * INC * 2);
  unsigned short* g = (unsigned short*)alloc((size_t)NN * OUTC * 2);
  int* deg = (int*)alloc(NN * 4);
  int* rowstart = (int*)alloc((NN + 1) * 4);
  int* cursor = (int*)alloc(NN * 4);
  int* colbuf = (int*)alloc(NE * 4);
  (void)ws_size; (void)in_sizes; (void)n_in; (void)out_size;

  k_xsum_part<<<256, 256, 0, stream>>>(x, xpartT, xb, deg, cursor);
  k_xsum_red<<<INC, 256, 0, stream>>>(xpartT, xsum, erow, deg);
  k_wc_part<<<dim3(OUTC / 4, JC), 256, 0, stream>>>(lin_w, W, att_w, part, uvpart);
  k_wc_red<<<OUTC / 4, 256, 0, stream>>>(part, uvpart, xsum, Wcb, gsum, u, v);
  k_gemm3<<<dim3(OUTC / 64, NN / 64), 256, 0, stream>>>(xb, Wcb, g);
  k_scan<<<1, 1024, 0, stream>>>(deg, rowstart);
  k_scatter<<<NE / 256, 256, 0, stream>>>(erow, ecol, rowstart, cursor, colbuf);
  k_sagg<<<NN / 4, 256, 0, stream>>>(x, u, v, gsum, g, rowstart, colbuf, out);
}

// Round 9
// 87.869 us; speedup vs baseline: 2.8562x; 1.2488x over previous
//
#include <hip/hip_runtime.h>
#include <hip/hip_bf16.h>

#define NN 8192
#define INC 256
#define OUTC 512
#define NE 262144
#define MAXD 128
#define JC 8
#define JLEN 64  // OUTC / JC

typedef __hip_bfloat16 bf16;
typedef short bf16x8 __attribute__((ext_vector_type(8)));
typedef float f32x4 __attribute__((ext_vector_type(4)));
typedef float f32x16 __attribute__((ext_vector_type(16)));

__device__ inline unsigned short f2bu(float f) {
  __hip_bfloat16 b = __float2bfloat16(f);
  return *reinterpret_cast<unsigned short*>(&b);
}
__device__ inline float blo(unsigned int x) { return __uint_as_float(x << 16); }
__device__ inline float bhi(unsigned int x) { return __uint_as_float(x & 0xffff0000u); }

// partial column sums of x (transposed out); fused x->bf16; zero deg.
// 256 blocks, 32 rows each. xpartT[k][b]
__global__ __launch_bounds__(256) void k_xsum_part(const float* __restrict__ x,
                                                   float* __restrict__ xpartT,
                                                   unsigned short* __restrict__ xb,
                                                   int* __restrict__ deg) {
  int t = threadIdx.x, b = blockIdx.x;  // 256 blocks
  int gid = b * 256 + t;
  if (gid < NN) deg[gid] = 0;
  float acc = 0.f;
  int r0 = b * (NN / 256);
  for (int r = r0; r < r0 + NN / 256; ++r) {
    float xv = x[r * INC + t];
    acc += xv;
    xb[r * INC + t] = f2bu(xv);
  }
  xpartT[t * 256 + b] = acc;
}

// 256 blocks: block k reduces xpartT[k][0..255]; fused edge-degree atomics
// whose return value IS the edge's slot within its row (-> eslot).
__global__ __launch_bounds__(256) void k_xsum_red(const float* __restrict__ xpartT,
                                                  float* __restrict__ xsum,
                                                  const int* __restrict__ erow,
                                                  int* __restrict__ deg,
                                                  int* __restrict__ eslot) {
  __shared__ float sred[4];
  int k = blockIdx.x, t = threadIdx.x;
  int l = t & 63, w = t >> 6;
  float r = xpartT[k * 256 + t];
#pragma unroll
  for (int off = 32; off > 0; off >>= 1) r += __shfl_xor(r, off);
  if (l == 0) sred[w] = r;
  // degree atomics: 65536 threads x 4 edges; atomic return = slot
  int e0 = (k * 256 + t) * 4;
  int4 ev = *(const int4*)(erow + e0);
  int4 sl;
  sl.x = atomicAdd(&deg[ev.x], 1);
  sl.y = atomicAdd(&deg[ev.y], 1);
  sl.z = atomicAdd(&deg[ev.z], 1);
  sl.w = atomicAdd(&deg[ev.w], 1);
  *(int4*)(eslot + e0) = sl;
  __syncthreads();
  if (t == 0) xsum[k] = sred[0] + sred[1] + sred[2] + sred[3];
}

// Stage 1 of Wc = lin_w @ W: j-chunked partials.
// grid (OUTC/4, JC) = (128, 8); 256 threads; 64-j chain per block.
__global__ __launch_bounds__(256) void k_wc_part(const float* __restrict__ lin_w,
                                                 const float* __restrict__ W,
                                                 const float* __restrict__ att_w,
                                                 float* __restrict__ part,
                                                 float* __restrict__ uvpart) {
  int k = threadIdx.x;
  int o0 = blockIdx.x * 4;
  int jc = blockIdx.y;
  int j0 = jc * JLEN;
  float a0 = 0.f, a1 = 0.f, a2 = 0.f, a3 = 0.f, su = 0.f, sv = 0.f;
  bool b0 = (blockIdx.x == 0);
  const float* lw0 = lin_w + (size_t)(o0 + 0) * OUTC + j0;
  const float* lw1 = lin_w + (size_t)(o0 + 1) * OUTC + j0;
  const float* lw2 = lin_w + (size_t)(o0 + 2) * OUTC + j0;
  const float* lw3 = lin_w + (size_t)(o0 + 3) * OUTC + j0;
#pragma unroll 8
  for (int jj = 0; jj < JLEN; ++jj) {
    float wv = W[(j0 + jj) * INC + k];
    a0 = fmaf(lw0[jj], wv, a0);
    a1 = fmaf(lw1[jj], wv, a1);
    a2 = fmaf(lw2[jj], wv, a2);
    a3 = fmaf(lw3[jj], wv, a3);
    if (b0) { su = fmaf(att_w[j0 + jj], wv, su); sv += wv; }
  }
  float* pb = part + ((size_t)jc * OUTC + o0) * INC + k;
  pb[0] = a0;
  pb[INC] = a1;
  pb[2 * INC] = a2;
  pb[3 * INC] = a3;
  if (b0) {
    uvpart[(jc * 2 + 0) * INC + k] = su;
    uvpart[(jc * 2 + 1) * INC + k] = sv;
  }
}

// Stage 2: blocks 0..127 reduce Wc partials -> Wcb bf16, gsum (block 0: u,v).
// Block 128: shfl-based exclusive scan deg[8192] -> rowstart[8193].
__global__ __launch_bounds__(256) void k_wc_red(const float* __restrict__ part,
                                                const float* __restrict__ uvpart,
                                                const float* __restrict__ xsum,
                                                unsigned short* __restrict__ Wcb,
                                                float* __restrict__ gsum,
                                                float* __restrict__ u,
                                                float* __restrict__ v,
                                                const int* __restrict__ deg,
                                                int* __restrict__ rowstart) {
  __shared__ float sred[4][4];
  __shared__ int wsum[4];
  int k = threadIdx.x;
  int l = k & 63, w = k >> 6;

  if (blockIdx.x == 128) {
    // exclusive scan: thread k owns deg[32k .. 32k+32)
    int base = k * 32;
    int loc[32];
    int s = 0;
#pragma unroll
    for (int j = 0; j < 32; j += 4) {
      int4 d4 = *(const int4*)(deg + base + j);
      loc[j] = s; s += d4.x;
      loc[j + 1] = s; s += d4.y;
      loc[j + 2] = s; s += d4.z;
      loc[j + 3] = s; s += d4.w;
    }
    int inc = s;
#pragma unroll
    for (int off = 1; off < 64; off <<= 1) {
      int up = __shfl_up(inc, off);
      if (l >= off) inc += up;
    }
    if (l == 63) wsum[w] = inc;
    __syncthreads();
    int woff = 0;
#pragma unroll
    for (int q = 0; q < 4; ++q)
      if (q < w) woff += wsum[q];
    int excl = woff + inc - s;
#pragma unroll
    for (int j = 0; j < 32; j += 4) {
      int4 o4;
      o4.x = excl + loc[j];
      o4.y = excl + loc[j + 1];
      o4.z = excl + loc[j + 2];
      o4.w = excl + loc[j + 3];
      *(int4*)(rowstart + base + j) = o4;
    }
    if (k == 255) rowstart[NN] = excl + s;
    return;
  }

  int o0 = blockIdx.x * 4;
#pragma unroll
  for (int oo = 0; oo < 4; ++oo) {
    float s = 0.f;
#pragma unroll
    for (int jc = 0; jc < JC; ++jc)
      s += part[((size_t)jc * OUTC + o0 + oo) * INC + k];
    Wcb[(size_t)(o0 + oo) * INC + k] = f2bu(s);
    float r = s * xsum[k];
#pragma unroll
    for (int off = 32; off > 0; off >>= 1) r += __shfl_xor(r, off);
    if (l == 0) sred[oo][w] = r;
  }
  __syncthreads();
  if (k < 4) gsum[o0 + k] = sred[k][0] + sred[k][1] + sred[k][2] + sred[k][3];
  if (blockIdx.x == 0) {
    float su = 0.f, sv = 0.f;
#pragma unroll
    for (int jc = 0; jc < JC; ++jc) {
      su += uvpart[(jc * 2 + 0) * INC + k];
      sv += uvpart[(jc * 2 + 1) * INC + k];
    }
    u[k] = su;
    v[k] = sv;
  }
}

// g = x @ Wc.T -> [8192,512] bf16. MFMA 32x32x16, 64x64 block tile, 2x2 waves.
// Epilogue: grid has exactly NE threads -> atomic-free CSR scatter (1 edge each).
__global__ __launch_bounds__(256) void k_gemm3(const unsigned short* __restrict__ xb,
                                               const unsigned short* __restrict__ wb,
                                               unsigned short* __restrict__ g,
                                               const int* __restrict__ erow,
                                               const int* __restrict__ ecol,
                                               const int* __restrict__ eslot,
                                               const int* __restrict__ rowstart,
                                               int* __restrict__ colbuf) {
  int w = threadIdx.x >> 6, l = threadIdx.x & 63;
  int wm = w >> 1, wn = w & 1;
  int r0 = blockIdx.y * 64 + wm * 32;
  int c0 = blockIdx.x * 64 + wn * 32;
  int lr = l & 31;
  int lk = (l >> 5) * 8;
  const unsigned short* pa = xb + (size_t)(r0 + lr) * INC + lk;
  const unsigned short* pb = wb + (size_t)(c0 + lr) * INC + lk;
  f32x16 acc = {};
#pragma unroll
  for (int k0 = 0; k0 < INC; k0 += 16) {
    bf16x8 a = *(const bf16x8*)(pa + k0);
    bf16x8 b = *(const bf16x8*)(pb + k0);
    acc = __builtin_amdgcn_mfma_f32_32x32x16_bf16(a, b, acc, 0, 0, 0);
  }
  // C/D: col = lane&31, row = (reg&3) + 8*(reg>>2) + 4*(lane>>5)
  int col = c0 + lr;
  int rbase = r0 + 4 * (l >> 5);
#pragma unroll
  for (int reg = 0; reg < 16; ++reg) {
    int row = rbase + (reg & 3) + 8 * (reg >> 2);
    g[(size_t)row * OUTC + col] = f2bu(acc[reg]);
  }
  // fused scatter: one edge per thread (1024 blocks * 256 = NE)
  int e = (blockIdx.y * gridDim.x + blockIdx.x) * 256 + threadIdx.x;
  int r = erow[e];
  colbuf[rowstart[r] + eslot[e]] = ecol[e];
}

// FUSED coeff+aggregate: one wave per row.
__global__ __launch_bounds__(256) void k_sagg(const float* __restrict__ x,
                                              const float* __restrict__ u,
                                              const float* __restrict__ v,
                                              const float* __restrict__ gsum,
                                              const unsigned short* __restrict__ g,
                                              const int* __restrict__ rowstart,
                                              const int* __restrict__ colbuf,
                                              float* __restrict__ out) {
  __shared__ int scols[4][MAXD];
  __shared__ float scoef[4][MAXD];
  int w = threadIdx.x >> 6, l = threadIdx.x & 63;
  int i = blockIdx.x * 4 + w;

  // alpha_i = leaky_relu((x_i.u)*(x_i.v))
  float su = 0.f, sv = 0.f;
#pragma unroll
  for (int kk = 0; kk < 4; ++kk) {
    int k = l + kk * 64;
    float xv = x[(size_t)i * INC + k];
    su = fmaf(xv, u[k], su);
    sv = fmaf(xv, v[k], sv);
  }
#pragma unroll
  for (int off = 32; off > 0; off >>= 1) {
    su += __shfl_xor(su, off);
    sv += __shfl_xor(sv, off);
  }
  float a = su * sv;
  float al = a > 0.f ? a : 0.2f * a;

  int s = rowstart[i];
  int d = rowstart[i + 1] - s;
  if (d > MAXD) d = MAXD;
  if (l < d) scols[w][l] = colbuf[s + l];
  int l2 = l + 64;
  if (l2 < d) scols[w][l2] = colbuf[s + l2];
  __syncthreads();
  int c0s = -1, c1s = -2;
  if (l < d) c0s = scols[w][l];
  if (l2 < d) c1s = scols[w][l2];
  int m0 = 0, m1 = 0, f0 = 1, f1 = 1;
  for (int q = 0; q < d; ++q) {
    int cq = scols[w][q];
    if (cq == c0s) { m0++; if (q < l) f0 = 0; }
    if (cq == c1s) { m1++; if (q < l2) f1 = 0; }
  }
  int mm = m0 > m1 ? m0 : m1;
#pragma unroll
  for (int off = 32; off > 0; off >>= 1) {
    int b = __shfl_xor(mm, off);
    if (b > mm) mm = b;
  }
  float M = (al > 0.f) ? al * (float)mm : 0.f;
  float eMn = expf(-M);
  float se = 0.f;
  int nc = 0;
  float cf0 = 0.f, cf1 = 0.f;
  if (l < d && f0) {
    float e0 = expf(al * (float)m0 - M);
    se += e0; nc++; cf0 = e0 - eMn;
  }
  if (l2 < d && f1) {
    float e1 = expf(al * (float)m1 - M);
    se += e1; nc++; cf1 = e1 - eMn;
  }
#pragma unroll
  for (int off = 32; off > 0; off >>= 1) {
    se += __shfl_xor(se, off);
    nc += __shfl_xor(nc, off);
  }
  float Z = (float)(NN - nc) * eMn + se;
  float invZ = 1.0f / Z;
  if (l < d) scoef[w][l] = cf0 * invZ;
  if (l2 < d) scoef[w][l2] = cf1 * invZ;
  float rs = eMn * invZ;

  // Phase B: gather. lane owns channels [8l, 8l+8); 2-way unrolled for MLP.
  int c0 = l * 8;
  float acc[8];
  float4 gs0 = *(const float4*)(gsum + c0);
  float4 gs1 = *(const float4*)(gsum + c0 + 4);
  acc[0] = rs * gs0.x; acc[1] = rs * gs0.y; acc[2] = rs * gs0.z; acc[3] = rs * gs0.w;
  acc[4] = rs * gs1.x; acc[5] = rs * gs1.y; acc[6] = rs * gs1.z; acc[7] = rs * gs1.w;
  int k = 0;
  for (; k + 2 <= d; k += 2) {
    int ca = scols[w][k], cb = scols[w][k + 1];
    float fa = scoef[w][k], fb = scoef[w][k + 1];
    uint4 pva = *(const uint4*)(g + (size_t)ca * OUTC + c0);
    uint4 pvb = *(const uint4*)(g + (size_t)cb * OUTC + c0);
    acc[0] = fmaf(fa, blo(pva.x), fmaf(fb, blo(pvb.x), acc[0]));
    acc[1] = fmaf(fa, bhi(pva.x), fmaf(fb, bhi(pvb.x), acc[1]));
    acc[2] = fmaf(fa, blo(pva.y), fmaf(fb, blo(pvb.y), acc[2]));
    acc[3] = fmaf(fa, bhi(pva.y), fmaf(fb, bhi(pvb.y), acc[3]));
    acc[4] = fmaf(fa, blo(pva.z), fmaf(fb, blo(pvb.z), acc[4]));
    acc[5] = fmaf(fa, bhi(pva.z), fmaf(fb, bhi(pvb.z), acc[5]));
    acc[6] = fmaf(fa, blo(pva.w), fmaf(fb, blo(pvb.w), acc[6]));
    acc[7] = fmaf(fa, bhi(pva.w), fmaf(fb, bhi(pvb.w), acc[7]));
  }
  if (k < d) {
    int ca = scols[w][k];
    float fa = scoef[w][k];
    uint4 pva = *(const uint4*)(g + (size_t)ca * OUTC + c0);
    acc[0] = fmaf(fa, blo(pva.x), acc[0]);
    acc[1] = fmaf(fa, bhi(pva.x), acc[1]);
    acc[2] = fmaf(fa, blo(pva.y), acc[2]);
    acc[3] = fmaf(fa, bhi(pva.y), acc[3]);
    acc[4] = fmaf(fa, blo(pva.z), acc[4]);
    acc[5] = fmaf(fa, bhi(pva.z), acc[5]);
    acc[6] = fmaf(fa, blo(pva.w), acc[6]);
    acc[7] = fmaf(fa, bhi(pva.w), acc[7]);
  }
  float4 o0, o1;
  o0.x = acc[0] > 0.f ? acc[0] : expm1f(acc[0]);
  o0.y = acc[1] > 0.f ? acc[1] : expm1f(acc[1]);
  o0.z = acc[2] > 0.f ? acc[2] : expm1f(acc[2]);
  o0.w = acc[3] > 0.f ? acc[3] : expm1f(acc[3]);
  o1.x = acc[4] > 0.f ? acc[4] : expm1f(acc[4]);
  o1.y = acc[5] > 0.f ? acc[5] : expm1f(acc[5]);
  o1.z = acc[6] > 0.f ? acc[6] : expm1f(acc[6]);
  o1.w = acc[7] > 0.f ? acc[7] : expm1f(acc[7]);
  float* po = out + (size_t)i * OUTC + c0;
  *(float4*)po = o0;
  *(float4*)(po + 4) = o1;
}

extern "C" void kernel_launch(void* const* d_in, const int* in_sizes, int n_in,
                              void* d_out, int out_size, void* d_ws, size_t ws_size,
                              hipStream_t stream) {
  const float* x = (const float*)d_in[0];
  const int* ei = (const int*)d_in[1];
  const float* W = (const float*)d_in[2];
  const float* att_w = (const float*)d_in[3];
  const float* lin_w = (const float*)d_in[4];
  float* out = (float*)d_out;
  const int* erow = ei;
  const int* ecol = ei + NE;

  char* ws = (char*)d_ws;
  size_t off = 0;
  auto alloc = [&](size_t bytes) {
    void* p = ws + off;
    off = (off + bytes + 255) & ~(size_t)255;
    return p;
  };
  float* u = (float*)alloc(INC * 4);
  float* v = (float*)alloc(INC * 4);
  float* xsum = (float*)alloc(INC * 4);
  float* xpartT = (float*)alloc(INC * 256 * 4);
  float* gsum = (float*)alloc(OUTC * 4);
  float* part = (float*)alloc((size_t)JC * OUTC * INC * 4);
  float* uvpart = (float*)alloc(JC * 2 * INC * 4);
  unsigned short* Wcb = (unsigned short*)alloc((size_t)OUTC * INC * 2);
  unsigned short* xb = (unsigned short*)alloc((size_t)NN * INC * 2);
  unsigned short* g = (unsigned short*)alloc((size_t)NN * OUTC * 2);
  int* deg = (int*)alloc(NN * 4);
  int* rowstart = (int*)alloc((NN + 1) * 4);
  int* eslot = (int*)alloc(NE * 4);
  int* colbuf = (int*)alloc(NE * 4);
  (void)ws_size; (void)in_sizes; (void)n_in; (void)out_size;

  k_xsum_part<<<256, 256, 0, stream>>>(x, xpartT, xb, deg);
  k_xsum_red<<<INC, 256, 0, stream>>>(xpartT, xsum, erow, deg, eslot);
  k_wc_part<<<dim3(OUTC / 4, JC), 256, 0, stream>>>(lin_w, W, att_w, part, uvpart);
  k_wc_red<<<OUTC / 4 + 1, 256, 0, stream>>>(part, uvpart, xsum, Wcb, gsum, u, v, deg, rowstart);
  k_gemm3<<<dim3(OUTC / 64, NN / 64), 256, 0, stream>>>(xb, Wcb, g, erow, ecol, eslot, rowstart, colbuf);
  k_sagg<<<NN / 4, 256, 0, stream>>>(x, u, v, gsum, g, rowstart, colbuf, out);
}